// Round 1
// 472.914 us; speedup vs baseline: 1.0191x; 1.0191x over previous
//
#include <hip/hip_runtime.h>

// 32 chained bottleneck blocks on x[16,256,64,64] fp32.
// Phase A: h1_0 = relu(W1_0 x + b1_0)           (reads x once)
// Phase B (x32): h2_k = relu(conv3x3 h1_k), store h2_k;
//                h1_{k+1} = relu(W1_{k+1} relu(W3_k h2_k + b3_k) + b1_{k+1})
// Phase C: out = sum_k relu(W3_k h2_k + b3_k)
//
// R7: phaseB 11.4us/dispatch vs ~2.5us VALU -> barrier/latency exposed at
// 2 blocks/CU. Shrink to 8x8 tiles: 1024 blocks = 4/CU, 16 waves/CU; conv
// spread over all 256 threads (oc x px). phaseC: 4ch x 8px per thread ->
// 1/4 DS instrs (all broadcast), weights pipelined in regs, chunked
// transpose (LDS 34.8->9.3 KB).

#define NN 16
#define HH 64
#define WW 64
#define CIN 256
#define CB 4
#define NBLK 32
#define PXT 32  // pixels per phaseC block

// bijective 64-px swizzle: spreads stride-4 float4 access over all 8 bank-quads
__device__ __forceinline__ int swz64(int i) { return i ^ ((i >> 2) & 7); }

// ---------------- Phase A: h1_0 = relu(W1_0 . x + b1_0) ------------------
// grid (64,16): blockIdx.x = y, blockIdx.y = n. 256 threads.
__global__ __launch_bounds__(256) void phaseA(
    const float* __restrict__ x, const float* __restrict__ w1,
    const float* __restrict__ b1, float* __restrict__ h1out) {
  __shared__ float4 w1s[CIN];    // [c] -> o components
  __shared__ float4 part[4][WW]; // [chunk][px] -> o components
  int tid = threadIdx.x;
  for (int i = tid; i < CIN * CB; i += 256) {
    int o = i >> 8, c = i & 255;
    ((float*)&w1s[c])[o] = w1[i]; // w1 global layout [o][c]
  }
  __syncthreads();
  int y = blockIdx.x, n = blockIdx.y;
  int chunk = tid >> 6, px = tid & 63;
  int cbase = chunk * 64;
  const float* xp = x + ((n * CIN + cbase) * HH + y) * WW + px;
  float s0 = 0.f, s1 = 0.f, s2 = 0.f, s3 = 0.f;
#pragma unroll 8
  for (int i = 0; i < 64; ++i) {
    float xv = xp[i * HH * WW];
    float4 wv = w1s[cbase + i];
    s0 = fmaf(xv, wv.x, s0);
    s1 = fmaf(xv, wv.y, s1);
    s2 = fmaf(xv, wv.z, s2);
    s3 = fmaf(xv, wv.w, s3);
  }
  part[chunk][px] = make_float4(s0, s1, s2, s3);
  __syncthreads();
  int px2 = tid >> 2, o = tid & 3;
  float v = ((float*)&part[0][px2])[o] + ((float*)&part[1][px2])[o] +
            ((float*)&part[2][px2])[o] + ((float*)&part[3][px2])[o];
  v += b1[o];
  h1out[((n * HH + y) * WW + px2) * CB + o] = fmaxf(v, 0.f);
}

// ---------------- Phase B: one bottleneck step ---------------------------
// 8x8 pixel tile, 256 threads, grid (8,8,16) = 1024 blocks = 4/CU.
// Conv: thread = (px, oc): 64 px x 4 oc, 36 fma each (no idle threads).
// Fused expand+reduce: q = tid>>4 owns 16 channels, pg = tid&15 owns 4 px.
// comb[16][64] partials (swizzled, aliases h1t) summed by thread=pixel.
__global__ __launch_bounds__(256, 4) void phaseB(
    const float* __restrict__ h1in, float* __restrict__ h1out,
    float* __restrict__ h2out,
    const float* __restrict__ w2, const float* __restrict__ b2,
    const float* __restrict__ w3, const float* __restrict__ b3,
    const float* __restrict__ w1n, const float* __restrict__ b1n,
    int compute_next) {
  __shared__ float4 wpk[CIN][2];  // [c][0]=w3[c][j], [c][1]=w1nT[c]  (8K)
  __shared__ float4 b3p[64];      // b3 packed by 4                   (1K)
  __shared__ float4 h2sb[64];     // h2 tile, swizzled                (1K)
  __shared__ __align__(16) float4 uni[1024]; // 16K: comb[16][64] / h1t[10][12]
  float4 (*h1t)[12] = (float4(*)[12])uni;
  float4* comb = (float4*)uni;

  int tid = threadIdx.x;
  int x0 = blockIdx.x * 8, y0 = blockIdx.y * 8;
  int n = blockIdx.z;

  // stage packed weights (one c per thread)
  {
    int c = tid;
    wpk[c][0] = *(const float4*)&w3[c * 4]; // w3 [c][jout]
    float4 wt;
    wt.x = w1n[c];          // w1n global [o][c]
    wt.y = w1n[256 + c];
    wt.z = w1n[512 + c];
    wt.w = w1n[768 + c];
    wpk[c][1] = wt;
    if (tid < 64) b3p[tid] = *(const float4*)&b3[tid * 4];
  }
  // stage input tile with zero halo (10 rows x 10 cols, padded to 12)
  if (tid < 100) {
    int cy = tid / 10, cx = tid % 10;
    int gy = y0 + cy - 1, gx = x0 + cx - 1;
    float4 v = make_float4(0.f, 0.f, 0.f, 0.f);
    if (gy >= 0 && gy < HH && gx >= 0 && gx < WW)
      v = *(const float4*)&h1in[((n * HH + gy) * WW + gx) * CB];
    h1t[cy][cx] = v;
  }
  __syncthreads(); // B1: tile + weights staged

  // 3x3 conv 4->4 + bias + relu: thread = (px, oc)
  {
    int oc = tid & 3, px = tid >> 2;
    int lx = px & 7, ly = px >> 3;
    float hacc = b2[oc];
#pragma unroll
    for (int p = 0; p < 9; ++p) {
      int dy = p / 3, dx = p % 3;
      float4 hv = h1t[ly + dy][lx + dx];
      const float* wr = &w2[oc * 36 + p]; // w2 [oc][i][3][3]
      hacc = fmaf(hv.x, wr[0], hacc);
      hacc = fmaf(hv.y, wr[9], hacc);
      hacc = fmaf(hv.z, wr[18], hacc);
      hacc = fmaf(hv.w, wr[27], hacc);
    }
    float h2v = fmaxf(hacc, 0.f);
    int gy = y0 + ly, gx = x0 + lx;
    h2out[((n * HH + gy) * WW + gx) * CB + oc] = h2v; // coalesced dwords
    ((float*)&h2sb[swz64(px)])[oc] = h2v;             // 2 lanes/bank: free
  }
  __syncthreads(); // B2: h2 tile staged; h1t dead -> comb may overwrite
  if (!compute_next) return; // last step: expand handled by phaseC

  int pg = tid & 15, q = tid >> 4; // 4 pixels, 16 channels per thread
  float4 h2r[4];
#pragma unroll
  for (int j = 0; j < 4; ++j) h2r[j] = h2sb[swz64(pg * 4 + j)];

  float4 tp[4];
#pragma unroll
  for (int j = 0; j < 4; ++j) tp[j] = make_float4(0.f, 0.f, 0.f, 0.f);

#pragma unroll
  for (int i4 = 0; i4 < 4; ++i4) { // 4 channels per iteration
    float4 bvv = b3p[q * 4 + i4];
#pragma unroll
    for (int s = 0; s < 4; ++s) {
      int c = q * 16 + i4 * 4 + s;
      float b = (s == 0) ? bvv.x : (s == 1) ? bvv.y : (s == 2) ? bvv.z : bvv.w;
      float4 w3v = wpk[c][0];
      float4 wnv = wpk[c][1];
#pragma unroll
      for (int j = 0; j < 4; ++j) {
        float u = fmaf(h2r[j].x, w3v.x, b);
        u = fmaf(h2r[j].y, w3v.y, u);
        u = fmaf(h2r[j].z, w3v.z, u);
        u = fmaf(h2r[j].w, w3v.w, u);
        float v = fmaxf(u, 0.f);
        tp[j].x = fmaf(v, wnv.x, tp[j].x);
        tp[j].y = fmaf(v, wnv.y, tp[j].y);
        tp[j].z = fmaf(v, wnv.z, tp[j].z);
        tp[j].w = fmaf(v, wnv.w, tp[j].w);
      }
    }
  }

#pragma unroll
  for (int j = 0; j < 4; ++j)
    comb[q * 64 + swz64(pg * 4 + j)] = tp[j];
  __syncthreads(); // B3: partials staged

  if (tid < 64) {
    int m = swz64(tid);
    float4 t = comb[m];
#pragma unroll
    for (int qq = 1; qq < 16; ++qq) {
      float4 pv = comb[qq * 64 + m];
      t.x += pv.x; t.y += pv.y; t.z += pv.z; t.w += pv.w;
    }
    float4 r = make_float4(fmaxf(t.x + b1n[0], 0.f), fmaxf(t.y + b1n[1], 0.f),
                           fmaxf(t.z + b1n[2], 0.f), fmaxf(t.w + b1n[3], 0.f));
    int gy = y0 + (tid >> 3), gx = x0 + (tid & 7);
    *(float4*)&h1out[((n * HH + gy) * WW + gx) * CB] = r;
  }
}

// ---------------- Phase C: acc = sum_k relu(W3_k h2_k + b3_k) ------------
// Thread = (4 channels, 8 pixels): 24 VALU per ds_read (vs 6), h2 reads are
// full-wave broadcasts (pg uniform per wave). Weights software-pipelined in
// registers across k. Chunked 64-row LDS transpose for coalesced stores.
// grid (128, 16) = 2048 blocks.
__global__ __launch_bounds__(256, 4) void phaseC(
    const float* __restrict__ h2buf, const float* __restrict__ w3g,
    const float* __restrict__ b3g, float* __restrict__ out) {
  __shared__ float4 h2s[2][PXT];
  __shared__ float tr[64][PXT + 1]; // 8.4K chunked transpose, +1 pad
  int tid = threadIdx.x;
  int cg = tid & 63;  // channel group: c0 = 4*cg
  int pg = tid >> 6;  // 0..3 -> pixels pg*8 .. pg*8+7
  int p0 = blockIdx.x * PXT; // flat pixel y*64+x
  int n = blockIdx.y;

  float acc0[8], acc1[8], acc2[8], acc3[8];
#pragma unroll
  for (int j = 0; j < 8; ++j) {
    acc0[j] = 0.f; acc1[j] = 0.f; acc2[j] = 0.f; acc3[j] = 0.f;
  }

  const float4* wp = (const float4*)&w3g[(cg * 4) * 4];
  float4 wv0 = wp[0], wv1 = wp[1], wv2 = wp[2], wv3 = wp[3];
  float4 bv = *(const float4*)&b3g[cg * 4];
  if (tid < PXT)
    h2s[0][tid] = *(const float4*)&h2buf[((0 * NN + n) * 4096 + p0 + tid) * 4];
  __syncthreads();

  for (int k = 0; k < NBLK; ++k) {
    float4 nw0, nw1, nw2, nw3, nbv; // prefetch k+1 (latency hidden by FMAs)
    if (k + 1 < NBLK) {
      const float4* np = (const float4*)&w3g[((k + 1) * 256 + cg * 4) * 4];
      nw0 = np[0]; nw1 = np[1]; nw2 = np[2]; nw3 = np[3];
      nbv = *(const float4*)&b3g[(k + 1) * 256 + cg * 4];
      if (tid < PXT)
        h2s[(k + 1) & 1][tid] =
            *(const float4*)&h2buf[(((k + 1) * NN + n) * 4096 + p0 + tid) * 4];
    }
    const float4* hb = &h2s[k & 1][pg * 8];
#pragma unroll
    for (int j = 0; j < 8; ++j) {
      float4 h = hb[j]; // full-wave broadcast ds_read_b128
      float u0 = fmaf(h.x, wv0.x, bv.x);
      u0 = fmaf(h.y, wv0.y, u0); u0 = fmaf(h.z, wv0.z, u0);
      u0 = fmaf(h.w, wv0.w, u0);
      acc0[j] += fmaxf(u0, 0.f);
      float u1 = fmaf(h.x, wv1.x, bv.y);
      u1 = fmaf(h.y, wv1.y, u1); u1 = fmaf(h.z, wv1.z, u1);
      u1 = fmaf(h.w, wv1.w, u1);
      acc1[j] += fmaxf(u1, 0.f);
      float u2 = fmaf(h.x, wv2.x, bv.z);
      u2 = fmaf(h.y, wv2.y, u2); u2 = fmaf(h.z, wv2.z, u2);
      u2 = fmaf(h.w, wv2.w, u2);
      acc2[j] += fmaxf(u2, 0.f);
      float u3 = fmaf(h.x, wv3.x, bv.w);
      u3 = fmaf(h.y, wv3.y, u3); u3 = fmaf(h.z, wv3.z, u3);
      u3 = fmaf(h.w, wv3.w, u3);
      acc3[j] += fmaxf(u3, 0.f);
    }
    __syncthreads();
    if (k + 1 < NBLK) {
      wv0 = nw0; wv1 = nw1; wv2 = nw2; wv3 = nw3; bv = nbv;
    }
  }

  // chunked transpose -> coalesced stores (4 chunks of 64 channels)
  int xi = tid & 31, cr = tid >> 5;
#pragma unroll 1
  for (int ch = 0; ch < 4; ++ch) {
    if ((cg >> 4) == ch) {
      int r0 = (cg & 15) * 4;
      int pb = pg * 8;
#pragma unroll
      for (int j = 0; j < 8; ++j) {
        tr[r0 + 0][pb + j] = acc0[j];
        tr[r0 + 1][pb + j] = acc1[j];
        tr[r0 + 2][pb + j] = acc2[j];
        tr[r0 + 3][pb + j] = acc3[j];
      }
    }
    __syncthreads();
#pragma unroll
    for (int j = 0; j < 8; ++j) {
      int cl = cr * 8 + j;
      out[(n * CIN + ch * 64 + cl) * (HH * WW) + p0 + xi] = tr[cl][xi];
    }
    __syncthreads();
  }
}

extern "C" void kernel_launch(void* const* d_in, const int* in_sizes, int n_in,
                              void* d_out, int out_size, void* d_ws, size_t ws_size,
                              hipStream_t stream) {
  const float* x  = (const float*)d_in[0];
  const float* w1 = (const float*)d_in[1]; // [32][4][256]
  const float* b1 = (const float*)d_in[2]; // [32][4]
  const float* w2 = (const float*)d_in[3]; // [32][4][4][3][3]
  const float* b2 = (const float*)d_in[4]; // [32][4]
  const float* w3 = (const float*)d_in[5]; // [32][256][4]
  const float* b3 = (const float*)d_in[6]; // [32][256]
  float* out = (float*)d_out;
  float* ws = (float*)d_ws;

  const int STATE = NN * HH * WW * CB; // 262144 floats = 1 MiB
  float* h1a = ws;
  float* h1b = ws + STATE;
  float* h2  = ws + 2 * STATE; // 32 MiB

  phaseA<<<dim3(HH, NN), 256, 0, stream>>>(x, w1, b1, h1a);
  for (int k = 0; k < NBLK; ++k) {
    const float* hin = (k & 1) ? h1b : h1a;
    float* hout = (k & 1) ? h1a : h1b;
    int kn = (k < NBLK - 1) ? k + 1 : NBLK - 1; // wrapped, unused on last
    phaseB<<<dim3(8, 8, NN), 256, 0, stream>>>(
        hin, hout, h2 + k * STATE,
        w2 + k * 144, b2 + k * CB, w3 + k * 1024, b3 + k * 256,
        w1 + kn * 1024, b1 + kn * CB, (k < NBLK - 1) ? 1 : 0);
  }
  phaseC<<<dim3((HH * WW) / PXT, NN), 256, 0, stream>>>(h2, w3, b3, out);
}